// Round 1
// 943.213 us; speedup vs baseline: 1.0071x; 1.0071x over previous
//
#include <hip/hip_runtime.h>

#define S_LEN 3072
#define NHQ 16
#define NKVH 8
#define HDIM 256
#define WIN 2048
#define QKV_COLS 8192

typedef __bf16 bf16x8 __attribute__((ext_vector_type(8)));
typedef float f32x4 __attribute__((ext_vector_type(4)));

__device__ __forceinline__ unsigned short f2bf(float f) {
    union { float f; unsigned u; } v; v.f = f;
    unsigned r = v.u + 0x7FFFu + ((v.u >> 16) & 1u);
    return (unsigned short)(r >> 16);
}
__device__ __forceinline__ float bf2f(unsigned short u) {
    union { unsigned u; float f; } v; v.u = ((unsigned)u) << 16; return v.f;
}

typedef __attribute__((address_space(3))) void lds_void_t;
typedef const __attribute__((address_space(1))) void glb_void_t;
__device__ __forceinline__ void async16(const void* g, void* l) {
    __builtin_amdgcn_global_load_lds((glb_void_t*)g, (lds_void_t*)l, 16, 0, 0);
}

// ---------------- fp32 -> bf16 cast ----------------
__global__ __launch_bounds__(256) void cast_bf16_kernel(const float* __restrict__ src,
                                                        unsigned short* __restrict__ dst,
                                                        int n) {
    int i = (blockIdx.x * 256 + threadIdx.x) * 4;
    if (i >= n) return;
    float4 v = *(const float4*)(src + i);
    ushort4 o;
    o.x = f2bf(v.x); o.y = f2bf(v.y); o.z = f2bf(v.z); o.w = f2bf(v.w);
    *(ushort4*)(dst + i) = o;
}

// ---------------- bf16 GEMM: C[M,N] = A[M,K] @ B[N,K]^T ----------------
template <int OUT_BF16>
__global__ __launch_bounds__(256) void gemm_bt(const unsigned short* __restrict__ A,
                                               const unsigned short* __restrict__ B,
                                               void* __restrict__ Cv,
                                               int N, int K) {
    __shared__ __align__(16) unsigned short At[128 * 32];
    __shared__ __align__(16) unsigned short Bt[128 * 32];
    const int tid = threadIdx.x;
    const int wid = tid >> 6, lane = tid & 63;
    const int ln = lane & 15, quad = lane >> 4;
    const int bm = blockIdx.y, bn = blockIdx.x;
    const int wm = wid >> 1, wn = wid & 1;

    const f32x4 fzero = {0.f, 0.f, 0.f, 0.f};
    f32x4 acc[4][4];
#pragma unroll
    for (int i = 0; i < 4; i++) {
#pragma unroll
        for (int j = 0; j < 4; j++) acc[i][j] = fzero;
    }

    const unsigned short* gA = A + (size_t)(bm * 128 + wid * 32 + (lane >> 2)) * K + (lane & 3) * 8;
    const unsigned short* gB = B + (size_t)(bn * 128 + wid * 32 + (lane >> 2)) * K + (lane & 3) * 8;
    unsigned short* lA = At + wid * 32 * 32;
    unsigned short* lB = Bt + wid * 32 * 32;

    for (int k0 = 0; k0 < K; k0 += 32) {
        async16(gA + k0, lA);
        async16(gA + k0 + 16 * K, lA + 16 * 32);
        async16(gB + k0, lB);
        async16(gB + k0 + 16 * K, lB + 16 * 32);
        __syncthreads();

        bf16x8 af[4], bfr[4];
#pragma unroll
        for (int mt = 0; mt < 4; mt++)
            af[mt] = *(const bf16x8*)(At + (wm * 64 + mt * 16 + ln) * 32 + quad * 8);
#pragma unroll
        for (int nt = 0; nt < 4; nt++)
            bfr[nt] = *(const bf16x8*)(Bt + (wn * 64 + nt * 16 + ln) * 32 + quad * 8);
#pragma unroll
        for (int mt = 0; mt < 4; mt++) {
#pragma unroll
            for (int nt = 0; nt < 4; nt++)
                acc[mt][nt] = __builtin_amdgcn_mfma_f32_16x16x32_bf16(af[mt], bfr[nt], acc[mt][nt], 0, 0, 0);
        }
        __syncthreads();
    }

    const int row0 = bm * 128 + wm * 64 + quad * 4;
    const int col0 = bn * 128 + wn * 64 + ln;
    if (OUT_BF16) {
        unsigned short* C = (unsigned short*)Cv;
#pragma unroll
        for (int mt = 0; mt < 4; mt++) {
#pragma unroll
            for (int nt = 0; nt < 4; nt++) {
#pragma unroll
                for (int rr = 0; rr < 4; rr++)
                    C[(size_t)(row0 + mt * 16 + rr) * N + col0 + nt * 16] = f2bf(acc[mt][nt][rr]);
            }
        }
    } else {
        float* C = (float*)Cv;
#pragma unroll
        for (int mt = 0; mt < 4; mt++) {
#pragma unroll
            for (int nt = 0; nt < 4; nt++) {
#pragma unroll
                for (int rr = 0; rr < 4; rr++)
                    C[(size_t)(row0 + mt * 16 + rr) * N + col0 + nt * 16] = acc[mt][nt][rr];
            }
        }
    }
}

// ---------------- RoPE for Q (scaled) and K ----------------
__global__ __launch_bounds__(256) void rope_kernel(const unsigned short* __restrict__ qkv,
                                                   const float* __restrict__ freqs,
                                                   const int* __restrict__ kvidx,
                                                   unsigned short* __restrict__ Qb,
                                                   unsigned short* __restrict__ Kb) {
    int t = blockIdx.x * 256 + threadIdx.x;
    int d = t & 127;
    int t2 = t >> 7;
    int hh = t2 % 24;
    int pos = t2 / 24;
    if (pos >= S_LEN) return;
    float2 cs = *(const float2*)(freqs + ((size_t)pos * 128 + d) * 2);
    if (hh < NHQ) {
        const unsigned short* src = qkv + (size_t)pos * QKV_COLS + hh * HDIM + d;
        float x1 = bf2f(src[0]), x2 = bf2f(src[128]);
        float o1 = (x1 * cs.x - x2 * cs.y) * 0.0625f;
        float o2 = (x1 * cs.y + x2 * cs.x) * 0.0625f;
        unsigned short* dst = Qb + ((size_t)hh * S_LEN + pos) * HDIM + d;
        dst[0] = f2bf(o1);
        dst[128] = f2bf(o2);
    } else {
        int kvh = hh - NHQ;
        const unsigned short* src = qkv + (size_t)pos * QKV_COLS + NHQ * HDIM + kvh * HDIM + d;
        float x1 = bf2f(src[0]), x2 = bf2f(src[128]);
        float o1 = x1 * cs.x - x2 * cs.y;
        float o2 = x1 * cs.y + x2 * cs.x;
        int wpos = kvidx[pos];
        unsigned short* dst = Kb + ((size_t)kvh * S_LEN + wpos) * HDIM + d;
        dst[0] = f2bf(o1);
        dst[128] = f2bf(o2);
    }
}

// ---------------- V transpose ----------------
__global__ __launch_bounds__(256) void vtrans_kernel(const unsigned short* __restrict__ qkv,
                                                     const int* __restrict__ kvidx,
                                                     unsigned short* __restrict__ Vbt) {
    __shared__ unsigned short T[64][72];
    int pos0 = blockIdx.x * 64;
    int c0 = blockIdx.y * 64;
    int a = threadIdx.x >> 6;
    int b = threadIdx.x & 63;
#pragma unroll
    for (int r = 0; r < 16; r++) {
        int pl = r * 4 + a;
        T[pl][b] = qkv[(size_t)(pos0 + pl) * QKV_COLS + 6144 + c0 + b];
    }
    __syncthreads();
    int wpos = kvidx[pos0 + b];
#pragma unroll
    for (int r = 0; r < 16; r++) {
        int cl = r * 4 + a;
        Vbt[(size_t)(c0 + cl) * S_LEN + wpos] = T[b][cl];
    }
}

// ---------------- flash attention v4 ----------------
// 768 blocks of 512 threads: (kv_head, chunk-unit). Each block processes BOTH
// q-heads sharing a KV head (waves 0-3 -> head 2kv, waves 4-7 -> head 2kv+1),
// so every staged K/V tile feeds 2x the compute of the old 4-wave version.
// K and V are staged via double-buffered global_load_lds DMA (linear LDS dest,
// pre-swizzled global source + XOR-swizzled reads -> 2-way = free bank access),
// with ONE raw s_barrier + vmcnt(0) per tile (raw barrier avoids __syncthreads'
// implicit vmcnt drain which would defeat the prefetch). P-relayout LDS is
// wave-private -> no mid-tile barrier.
// Chunk decode / softcap softmax / fixed-max combine logic unchanged.
__global__ __launch_bounds__(512, 4) void attn_kernel(const unsigned short* __restrict__ Qb,
                                                      const unsigned short* __restrict__ Kb,
                                                      const unsigned short* __restrict__ Vbt,
                                                      float* __restrict__ Acc,
                                                      float* __restrict__ Ps,
                                                      unsigned short* __restrict__ attn_out) {
    __shared__ __align__(16) unsigned short Kl[2][32 * 256];   // 2 x 16 KB, keys x dims
    __shared__ __align__(16) unsigned short Vl[2][256 * 32];   // 2 x 16 KB, dims x keys
    __shared__ __align__(16) unsigned short Plb[8][16][40];    // per-wave P relayout

    // decode (kv, it) — reversed so long chunks dispatch first
    const int kv = blockIdx.x / 96;
    const int it = 95 - (blockIdx.x % 96);
    int qb, sub, nc;
    if (it < 16)      { qb = it; sub = 0; nc = 1; }
    else if (it < 48) { int e = it - 16; qb = 16 + (e >> 1); sub = e & 1; nc = 2; }
    else              { int e = it - 48; qb = 32 + e / 3; sub = e % 3; nc = 3; }

    const int q0 = qb * 64;
    const int tid = threadIdx.x;
    const int wid = tid >> 6, lane = tid & 63;
    const int ln = lane & 15, quad = lane >> 4;
    const int h = kv * 2 + (wid >> 2);       // waves 0-3: head 2kv, waves 4-7: head 2kv+1
    const int wrow = (wid & 3) * 16;

    bf16x8 qf[8];
    {
        const unsigned short* qrow = Qb + ((size_t)h * S_LEN + q0 + wrow + ln) * HDIM;
#pragma unroll
        for (int k0 = 0; k0 < 8; k0++)
            qf[k0] = *(const bf16x8*)(qrow + k0 * 32 + quad * 8);
    }

    const f32x4 fzero = {0.f, 0.f, 0.f, 0.f};
    f32x4 acc[16];
#pragma unroll
    for (int t = 0; t < 16; t++) acc[t] = fzero;
    float ps[4] = {0.f, 0.f, 0.f, 0.f};

    const int imin = q0 + wrow;
    const int imax = imin + 15;
    const int irow = imin + quad * 4;

    const int t_lo = (q0 >= WIN) ? ((q0 - (WIN - 1)) >> 5) : 0;
    const int t_hi = (q0 + 63) >> 5;
    const int tn = t_hi - t_lo + 1;
    const int ts = t_lo + (tn * sub) / nc;
    const int te = t_lo + (tn * (sub + 1)) / nc;

    // ---- DMA staging source pointers (p0-invariant part) ----
    // K tile: 1024 chunks of 16B. LDS chunk g = (call*512 + tid): row=g>>5 (key),
    // pos=g&31. Content = K[row][pos ^ (row&7)] -> read at pos c^(row&7) gives K[row][c].
    const unsigned short* kSrcA = Kb + ((size_t)kv * S_LEN + (tid >> 5)) * HDIM
                                  + ((tid & 31) ^ ((tid >> 5) & 7)) * 8;
    // V tile: row=g>>2 (dim), pos=g&3. Content = V^T[row][pos ^ ((row>>1)&3)].
    const unsigned short* vSrcA = Vbt + ((size_t)kv * HDIM + (tid >> 2)) * S_LEN
                                  + ((tid & 3) ^ ((tid >> 3) & 3)) * 8;

    // prologue: stage first tile into buffer 0
    {
        const int p0s = ts * 32;
        const unsigned short* ks = kSrcA + (size_t)p0s * HDIM;
        const unsigned short* vs = vSrcA + p0s;
        async16(ks,                 &Kl[0][tid * 8]);
        async16(ks + 16 * HDIM,     &Kl[0][(512 + tid) * 8]);
        async16(vs,                 &Vl[0][tid * 8]);
        async16(vs + 128 * S_LEN,   &Vl[0][(512 + tid) * 8]);
    }

    const int kswz = (ln & 7);
    const unsigned short* vbb_off = (const unsigned short*)0; (void)vbb_off;
    int cur = 0;

    for (int tt = ts; tt < te; tt++) {
        // wait own DMA for buf[cur], then block-wide barrier -> buf[cur] fully visible.
        asm volatile("s_waitcnt vmcnt(0)" ::: "memory");
        __builtin_amdgcn_s_barrier();
        asm volatile("" ::: "memory");

        // prefetch next tile into buf[cur^1] (safe: cur^1 last read before the barrier above)
        if (tt + 1 < te) {
            const int p0n = (tt + 1) * 32;
            const unsigned short* ks = kSrcA + (size_t)p0n * HDIM;
            const unsigned short* vs = vSrcA + p0n;
            async16(ks,                 &Kl[cur ^ 1][tid * 8]);
            async16(ks + 16 * HDIM,     &Kl[cur ^ 1][(512 + tid) * 8]);
            async16(vs,                 &Vl[cur ^ 1][tid * 8]);
            async16(vs + 128 * S_LEN,   &Vl[cur ^ 1][(512 + tid) * 8]);
        }

        const int p0 = tt * 32;
        const bool live = (p0 <= imax) && (p0 + 31 >= imin - WIN + 1);
        if (live) {
            const unsigned short* kb = Kl[cur];
            f32x4 s0 = fzero, s1 = fzero;
#pragma unroll
            for (int k0 = 0; k0 < 8; k0++) {
                const int cp = (((k0 * 4 + quad) ^ kswz) << 3);
                bf16x8 b0 = *(const bf16x8*)(kb + ln * HDIM + cp);
                s0 = __builtin_amdgcn_mfma_f32_16x16x32_bf16(qf[k0], b0, s0, 0, 0, 0);
            }
#pragma unroll
            for (int k0 = 0; k0 < 8; k0++) {
                const int cp = (((k0 * 4 + quad) ^ kswz) << 3);
                bf16x8 b1 = *(const bf16x8*)(kb + (16 + ln) * HDIM + cp);
                s1 = __builtin_amdgcn_mfma_f32_16x16x32_bf16(qf[k0], b1, s1, 0, 0, 0);
            }

            const bool full = (p0 + 31 <= imin) && (p0 >= imax - WIN + 1);
#pragma unroll
            for (int r = 0; r < 4; r++) {
                float z0 = __expf(s0[r] * 0.04f);
                float z1 = __expf(s1[r] * 0.04f);
                float t0 = fmaf(-100.f, __builtin_amdgcn_rcpf(z0 + 1.f), 50.f);
                float t1 = fmaf(-100.f, __builtin_amdgcn_rcpf(z1 + 1.f), 50.f);
                float p0v = __expf(t0);
                float p1v = __expf(t1);
                if (!full) {
                    const int i = irow + r;
                    int j0 = p0 + ln, j1 = p0 + 16 + ln;
                    p0v = ((j0 <= i) && (j0 + WIN > i)) ? p0v : 0.f;
                    p1v = ((j1 <= i) && (j1 + WIN > i)) ? p1v : 0.f;
                }
                ps[r] += p0v + p1v;
                Plb[wid][quad * 4 + r][ln] = f2bf(p0v);
                Plb[wid][quad * 4 + r][16 + ln] = f2bf(p1v);
            }
            // Plb is wave-private: lgkmcnt (compiler-inserted) suffices, no barrier.
            bf16x8 pa = *(const bf16x8*)(&Plb[wid][ln][quad * 8]);
            const unsigned short* vbb = Vl[cur] + ln * 32 + ((quad ^ ((ln >> 1) & 3)) << 3);
#pragma unroll
            for (int t = 0; t < 16; t++) {
                bf16x8 vb = *(const bf16x8*)(vbb + t * 512);
                acc[t] = __builtin_amdgcn_mfma_f32_16x16x32_bf16(pa, vb, acc[t], 0, 0, 0);
            }
        }
        cur ^= 1;
    }

    // reduce ps over the 16 lanes of each quad-group
    float psr[4];
#pragma unroll
    for (int r = 0; r < 4; r++) {
        float s = ps[r];
#pragma unroll
        for (int o = 1; o <= 8; o <<= 1)
            s += __shfl_xor(s, o);
        psr[r] = s;
    }

    if (nc == 1) {
#pragma unroll
        for (int t = 0; t < 16; t++) {
#pragma unroll
            for (int r = 0; r < 4; r++) {
                float o = acc[t][r] * __builtin_amdgcn_rcpf(psr[r]);
                attn_out[(size_t)(irow + r) * 4096 + h * HDIM + t * 16 + ln] = f2bf(o);
            }
        }
    } else {
        if (ln == 0) {
#pragma unroll
            for (int r = 0; r < 4; r++)
                atomicAdd(&Ps[h * S_LEN + irow + r], psr[r]);
        }
#pragma unroll
        for (int t = 0; t < 16; t++) {
#pragma unroll
            for (int r = 0; r < 4; r++)
                atomicAdd(&Acc[((size_t)h * S_LEN + irow + r) * HDIM + t * 16 + ln], acc[t][r]);
        }
    }
}

// ---------------- normalize chunked rows (pos >= 1024) ----------------
__global__ __launch_bounds__(256) void norm_kernel(const float* __restrict__ Acc,
                                                   const float* __restrict__ Ps,
                                                   unsigned short* __restrict__ attn_out) {
    int row = blockIdx.x * 4 + (threadIdx.x >> 6);   // over 16*2048 rows
    int lane = threadIdx.x & 63;
    int h = row >> 11;
    int pos = 1024 + (row & 2047);
    float4 a = *(const float4*)(Acc + ((size_t)h * S_LEN + pos) * HDIM + lane * 4);
    float inv = __builtin_amdgcn_rcpf(Ps[h * S_LEN + pos]);
    ushort4 o;
    o.x = f2bf(a.x * inv); o.y = f2bf(a.y * inv);
    o.z = f2bf(a.z * inv); o.w = f2bf(a.w * inv);
    *(ushort4*)(attn_out + (size_t)pos * 4096 + h * HDIM + lane * 4) = o;
}

// ---------------- launch ----------------
extern "C" void kernel_launch(void* const* d_in, const int* in_sizes, int n_in,
                              void* d_out, int out_size, void* d_ws, size_t ws_size,
                              hipStream_t stream) {
    (void)in_sizes; (void)n_in; (void)out_size; (void)ws_size;
    const float* hidden = (const float*)d_in[0];
    const float* freqs  = (const float*)d_in[1];
    const int* kvidx    = (const int*)d_in[2];
    const float* qkv_w  = (const float*)d_in[6];
    const float* o_w    = (const float*)d_in[7];
    float* out = (float*)d_out;

    char* ws = (char*)d_ws;
    unsigned short* hs_bf   = (unsigned short*)(ws);                 // 22.0 MB (gemm1 input; Ps reuses after)
    unsigned short* w1_bf   = (unsigned short*)(ws + 22020096);
    unsigned short* w2_bf   = (unsigned short*)(ws + 80740352);
    unsigned short* qkv_bf  = (unsigned short*)(ws + 110100480);     // 50.3 MB (Acc reuses after rope/vtrans)
    unsigned short* Qb      = (unsigned short*)(ws + 160432128);
    unsigned short* Kb      = (unsigned short*)(ws + 185597952);
    unsigned short* Vbt     = (unsigned short*)(ws + 198180864);
    unsigned short* attn_bf = (unsigned short*)(ws + 210763776);

    float* Acc = (float*)(ws + 110100480);   // 16*3072*256*4 = 50,331,648 B exactly
    float* Ps  = (float*)(ws);               // 16*3072*4 = 196,608 B (over retired hs_bf)

    cast_bf16_kernel<<<10752, 256, 0, stream>>>(hidden, hs_bf, 11010048);
    cast_bf16_kernel<<<28672, 256, 0, stream>>>(qkv_w, w1_bf, 29360128);
    cast_bf16_kernel<<<14336, 256, 0, stream>>>(o_w, w2_bf, 14680064);

    gemm_bt<1><<<dim3(64, 24), 256, 0, stream>>>(hs_bf, w1_bf, (void*)qkv_bf, 8192, 3584);

    rope_kernel<<<36864, 256, 0, stream>>>(qkv_bf, freqs, kvidx, Qb, Kb);
    vtrans_kernel<<<dim3(48, 32), 256, 0, stream>>>(qkv_bf, kvidx, Vbt);

    // zero partial buffers (regions retired by gemm1/rope/vtrans above)
    hipMemsetAsync(Acc, 0, (size_t)16 * 3072 * 256 * 4, stream);
    hipMemsetAsync(Ps, 0, (size_t)16 * 3072 * 4, stream);

    attn_kernel<<<768, 512, 0, stream>>>(Qb, Kb, Vbt, Acc, Ps, attn_bf);
    norm_kernel<<<8192, 256, 0, stream>>>(Acc, Ps, attn_bf);

    gemm_bt<0><<<dim3(28, 24), 256, 0, stream>>>(attn_bf, w2_bf, (void*)out, 3584, 4096);
}